// Round 1
// baseline (2370.339 us; speedup 1.0000x reference)
//
#include <hip/hip_runtime.h>
#include <stdint.h>

typedef unsigned short ushort;
typedef __bf16 bf16x8 __attribute__((ext_vector_type(8)));
typedef float f32x4 __attribute__((ext_vector_type(4)));
typedef ushort ushort8 __attribute__((ext_vector_type(8)));

__device__ __forceinline__ float bf2f(ushort u) {
  union { unsigned int i; float f; } v; v.i = ((unsigned int)u) << 16; return v.f;
}
__device__ __forceinline__ ushort f2bf(float f) {
  union { float f; unsigned int i; } v; v.f = f;
  unsigned int r = v.i + 0x7fffu + ((v.i >> 16) & 1u);
  return (ushort)(r >> 16);
}

// Geometry: x (2,3,360,640); patches 5x5 -> N = 2*72*128 = 18432
// feat per patch: (256,3,3) stored bf16 as [n][k], k = pos*256 + c  (pos = i*3+j)
// kern GEMM: C[18432][896] = feat[18432][2304] * Bt[896][2304]^T  (cols 0..863 kern, 864..895 badp)

// ---------------- pack: Bt[896][2304] bf16 + bias896 ----------------
__global__ __launch_bounds__(256) void pack_kernel(
    const float* __restrict__ w_kern, const float* __restrict__ b_kern,
    const float* __restrict__ w_badp, const float* __restrict__ b_badp,
    ushort* __restrict__ Bt, float* __restrict__ bias896) {
  int idx = blockIdx.x * 256 + threadIdx.x;
  const int total = 896 * 2304;
  if (idx < total) {
    int o = idx / 2304, k = idx - o * 2304;
    int c = k & 255, pos = k >> 8;
    float v = (o < 864) ? w_kern[(o * 256 + c) * 9 + pos]
                        : w_badp[((o - 864) * 256 + c) * 9 + pos];
    Bt[idx] = f2bf(v);
  } else if (idx < total + 896) {
    int o = idx - total;
    bias896[o] = (o < 864) ? b_kern[o] : b_badp[o - 864];
  }
}

// ---------------- feat: per-patch 3x3 VALID conv, 256 ch, relu, bf16 ----------------
__global__ __launch_bounds__(256) void feat_kernel(
    const float* __restrict__ x, const float* __restrict__ w_feat,
    const float* __restrict__ b_feat, ushort* __restrict__ feat) {
  __shared__ float xp[4][3][5][5];
  const int t = threadIdx.x;
  const int n0 = blockIdx.x * 4;
  for (int e = t; e < 300; e += 256) {
    int p = e / 75, rem = e - p * 75;
    int ci = rem / 25, r = rem - ci * 25, i = r / 5, j = r - i * 5;
    int n = n0 + p;
    int b = n / 9216, ph = (n >> 7) % 72, pw = n & 127;
    xp[p][ci][i][j] = x[((b * 3 + ci) * 360 + ph * 5 + i) * 640 + pw * 5 + j];
  }
  float wf[27];
#pragma unroll
  for (int m = 0; m < 27; ++m) wf[m] = w_feat[t * 27 + m];
  const float bv = b_feat[t];
  __syncthreads();
  for (int p = 0; p < 4; ++p) {
    ushort* dst = feat + (size_t)(n0 + p) * 2304 + t;
#pragma unroll
    for (int pi = 0; pi < 3; ++pi)
#pragma unroll
      for (int pj = 0; pj < 3; ++pj) {
        float acc = bv;
#pragma unroll
        for (int ci = 0; ci < 3; ++ci)
#pragma unroll
          for (int ki = 0; ki < 3; ++ki)
#pragma unroll
            for (int kj = 0; kj < 3; ++kj)
              acc = fmaf(xp[p][ci][pi + ki][pj + kj], wf[ci * 9 + ki * 3 + kj], acc);
        dst[(pi * 3 + pj) * 256] = f2bf(fmaxf(acc, 0.f));
      }
  }
}

// ---------------- kern+badp GEMM: MFMA bf16, 128x128 tile, BK=32 ----------------
// A[m][k] bf16 row-major, Bt[n][k] bf16 row-major (B^T input), C bf16 [m][896] (+bias)
__global__ __launch_bounds__(256) void gemm_kernel(
    const ushort* __restrict__ A, const ushort* __restrict__ Bt,
    const float* __restrict__ bias, ushort* __restrict__ C) {
  const int K = 2304, N = 896;
  __shared__ __align__(16) ushort lA[128 * 32];
  __shared__ __align__(16) ushort lB[128 * 32];
  const int m0 = blockIdx.x * 128, n0 = blockIdx.y * 128;
  const int t = threadIdx.x;
  const int lane = t & 63, wave = t >> 6;
  const int wm = wave >> 1, wn = wave & 1;
  f32x4 acc[4][4] = {};
  const ushort* gA = A + (m0 + (t >> 2)) * K + (t & 3) * 8;
  const ushort* gB = Bt + (n0 + (t >> 2)) * K + (t & 3) * 8;
  ushort* sA = &lA[t * 8];
  ushort* sB = &lB[t * 8];
  const int aoff = (wm * 64 + (lane & 15)) * 32 + (lane >> 4) * 8;
  const int boff = (wn * 64 + (lane & 15)) * 32 + (lane >> 4) * 8;
  for (int kt = 0; kt < K; kt += 32) {
    ushort8 a0 = *(const ushort8*)(gA + kt);
    ushort8 a1 = *(const ushort8*)(gA + 64 * K + kt);
    ushort8 b0 = *(const ushort8*)(gB + kt);
    ushort8 b1 = *(const ushort8*)(gB + 64 * K + kt);
    __syncthreads();
    *(ushort8*)sA = a0;
    *(ushort8*)(sA + 2048) = a1;
    *(ushort8*)sB = b0;
    *(ushort8*)(sB + 2048) = b1;
    __syncthreads();
    bf16x8 af[4], bfr[4];
#pragma unroll
    for (int mi = 0; mi < 4; ++mi) {
      ushort8 tmp = *(const ushort8*)(&lA[aoff + mi * 512]);
      af[mi] = __builtin_bit_cast(bf16x8, tmp);
    }
#pragma unroll
    for (int ni = 0; ni < 4; ++ni) {
      ushort8 tmp = *(const ushort8*)(&lB[boff + ni * 512]);
      bfr[ni] = __builtin_bit_cast(bf16x8, tmp);
    }
#pragma unroll
    for (int mi = 0; mi < 4; ++mi)
#pragma unroll
      for (int ni = 0; ni < 4; ++ni)
        acc[mi][ni] = __builtin_amdgcn_mfma_f32_16x16x32_bf16(af[mi], bfr[ni], acc[mi][ni], 0, 0, 0);
  }
  // C/D layout (verified m89/m91): col = lane&15, row = (lane>>4)*4 + r
#pragma unroll
  for (int ni = 0; ni < 4; ++ni) {
    int col = n0 + wn * 64 + ni * 16 + (lane & 15);
    float bv = bias[col];
#pragma unroll
    for (int mi = 0; mi < 4; ++mi) {
      int row0 = m0 + wm * 64 + mi * 16 + (lane >> 4) * 4;
#pragma unroll
      for (int r = 0; r < 4; ++r)
        C[(size_t)(row0 + r) * N + col] = f2bf(acc[mi][ni][r] + bv);
    }
  }
}

// ---------------- apply: einsum(xu,kern) + bias, relu, batch_to_space ----------------
__global__ __launch_bounds__(256) void apply_kernel(
    const float* __restrict__ x, const ushort* __restrict__ kernbias,
    ushort* __restrict__ sp) {
  __shared__ float xp[8][3][7][7];      // zero-padded patches
  __shared__ ushort outl[8][32][25];
  const int t = threadIdx.x;
  const int n0 = blockIdx.x * 8;        // 8 consecutive pw patches (same b, ph)
  const int b = n0 / 9216, ph = (n0 >> 7) % 72, pw0 = n0 & 127;
  for (int e = t; e < 8 * 3 * 49; e += 256) ((float*)xp)[e] = 0.f;
  __syncthreads();
  for (int e = t; e < 600; e += 256) {
    int p = e / 75, rem = e - p * 75;
    int ci = rem / 25, r = rem - ci * 25, i = r / 5, j = r - i * 5;
    xp[p][ci][i + 1][j + 1] = x[((b * 3 + ci) * 360 + ph * 5 + i) * 640 + (pw0 + p) * 5 + j];
  }
  __syncthreads();
  const int p = t >> 5, f = t & 31;
  const int n = n0 + p;
  float kk[27];
#pragma unroll
  for (int k = 0; k < 27; ++k) kk[k] = bf2f(kernbias[(size_t)n * 896 + f * 27 + k]);
  const float bv = bf2f(kernbias[(size_t)n * 896 + 864 + f]);
  for (int l = 0; l < 25; ++l) {
    int li = l / 5, lj = l - li * 5;
    float s = bv;
#pragma unroll
    for (int k = 0; k < 27; ++k) {
      int ci = k / 9, rm = k - ci * 9, ki = rm / 3, kj = rm - ki * 3;
      s = fmaf(xp[p][ci][li + ki][lj + kj], kk[k], s);
    }
    outl[p][f][l] = f2bf(fmaxf(s, 0.f));
  }
  __syncthreads();
  for (int e = t; e < 6400; e += 256) {
    int f2 = e / 200, rm = e - f2 * 200, i = rm / 40, c40 = rm - i * 40;
    int pp = c40 / 5, j = c40 - pp * 5;
    sp[((size_t)(b * 32 + f2) * 360 + ph * 5 + i) * 640 + pw0 * 5 + c40] = outl[pp][f2][i * 5 + j];
  }
}

// ---------------- conv1: 5x5, 32->128, SAME, relu. bf16 in/out, fp32 accum ----------------
__global__ __launch_bounds__(256) void conv1_kernel(
    const ushort* __restrict__ sp, const float* __restrict__ w1,
    const float* __restrict__ b1, ushort* __restrict__ h1) {
  __shared__ float xt[8][20][37];
  __shared__ float wt[32][8][25];
  const int tw0 = blockIdx.x * 32, th0 = blockIdx.y * 16;
  const int b = blockIdx.z >> 2, ocb = blockIdx.z & 3;
  const int t = threadIdx.x;
  const int slot = t & 63, ocg = t >> 6;
  const int gx = slot & 3, gy = slot >> 2;
  float acc[8][8];
#pragma unroll
  for (int px = 0; px < 8; ++px)
#pragma unroll
    for (int o = 0; o < 8; ++o) acc[px][o] = 0.f;
  for (int cc = 0; cc < 4; ++cc) {
    __syncthreads();
    for (int e = t; e < 8 * 20 * 36; e += 256) {
      int ci = e / 720, rm = e - ci * 720, r = rm / 36, cL = rm - r * 36;
      int hh = th0 + r - 2, ww = tw0 + cL - 2;
      float v = 0.f;
      if (hh >= 0 && hh < 360 && ww >= 0 && ww < 640)
        v = bf2f(sp[((b * 32 + cc * 8 + ci) * 360 + hh) * 640 + ww]);
      xt[ci][r][cL] = v;
    }
    for (int e = t; e < 32 * 8 * 25; e += 256) {
      int o = e / 200, rm = e - o * 200, ci = rm / 25, k = rm - ci * 25;
      wt[o][ci][k] = w1[((ocb * 32 + o) * 32 + cc * 8 + ci) * 25 + k];
    }
    __syncthreads();
#pragma unroll 1
    for (int ci = 0; ci < 8; ++ci) {
#pragma unroll
      for (int ki = 0; ki < 5; ++ki) {
        float xv[12];
#pragma unroll
        for (int u = 0; u < 12; ++u) xv[u] = xt[ci][gy + ki][gx * 8 + u];
#pragma unroll
        for (int kj = 0; kj < 5; ++kj) {
          float wr[8];
#pragma unroll
          for (int o = 0; o < 8; ++o) wr[o] = wt[ocg * 8 + o][ci][ki * 5 + kj];
#pragma unroll
          for (int px = 0; px < 8; ++px)
#pragma unroll
            for (int o = 0; o < 8; ++o)
              acc[px][o] = fmaf(xv[px + kj], wr[o], acc[px][o]);
        }
      }
    }
  }
  const int hh = th0 + gy;
  if (hh < 360) {
#pragma unroll
    for (int o = 0; o < 8; ++o) {
      int oc = ocb * 32 + ocg * 8 + o;
      float bv = b1[oc];
      ushort8 pk;
#pragma unroll
      for (int px = 0; px < 8; ++px) pk[px] = f2bf(fmaxf(acc[px][o] + bv, 0.f));
      *(ushort8*)(&h1[((size_t)(b * 128 + oc) * 360 + hh) * 640 + tw0 + gx * 8]) = pk;
    }
  }
}

// ---------------- conv2: 3x3, 128->32, SAME, relu ----------------
__global__ __launch_bounds__(256) void conv2_kernel(
    const ushort* __restrict__ h1, const float* __restrict__ w2,
    const float* __restrict__ b2, ushort* __restrict__ h2) {
  __shared__ float xt[8][18][35];
  __shared__ float wt[32][8][9];
  const int tw0 = blockIdx.x * 32, th0 = blockIdx.y * 16;
  const int b = blockIdx.z;
  const int t = threadIdx.x;
  const int slot = t & 63, ocg = t >> 6;
  const int gx = slot & 3, gy = slot >> 2;
  float acc[8][8];
#pragma unroll
  for (int px = 0; px < 8; ++px)
#pragma unroll
    for (int o = 0; o < 8; ++o) acc[px][o] = 0.f;
  for (int cc = 0; cc < 16; ++cc) {
    __syncthreads();
    for (int e = t; e < 8 * 18 * 34; e += 256) {
      int ci = e / 612, rm = e - ci * 612, r = rm / 34, cL = rm - r * 34;
      int hh = th0 + r - 1, ww = tw0 + cL - 1;
      float v = 0.f;
      if (hh >= 0 && hh < 360 && ww >= 0 && ww < 640)
        v = bf2f(h1[((size_t)(b * 128 + cc * 8 + ci) * 360 + hh) * 640 + ww]);
      xt[ci][r][cL] = v;
    }
    for (int e = t; e < 32 * 8 * 9; e += 256) {
      int o = e / 72, rm = e - o * 72, ci = rm / 9, k = rm - ci * 9;
      wt[o][ci][k] = w2[(o * 128 + cc * 8 + ci) * 9 + k];
    }
    __syncthreads();
#pragma unroll 1
    for (int ci = 0; ci < 8; ++ci) {
#pragma unroll
      for (int ki = 0; ki < 3; ++ki) {
        float xv[10];
#pragma unroll
        for (int u = 0; u < 10; ++u) xv[u] = xt[ci][gy + ki][gx * 8 + u];
#pragma unroll
        for (int kj = 0; kj < 3; ++kj) {
          float wr[8];
#pragma unroll
          for (int o = 0; o < 8; ++o) wr[o] = wt[ocg * 8 + o][ci][ki * 3 + kj];
#pragma unroll
          for (int px = 0; px < 8; ++px)
#pragma unroll
            for (int o = 0; o < 8; ++o)
              acc[px][o] = fmaf(xv[px + kj], wr[o], acc[px][o]);
        }
      }
    }
  }
  const int hh = th0 + gy;
  if (hh < 360) {
#pragma unroll
    for (int o = 0; o < 8; ++o) {
      int oc = ocg * 8 + o;
      float bv = b2[oc];
      ushort8 pk;
#pragma unroll
      for (int px = 0; px < 8; ++px) pk[px] = f2bf(fmaxf(acc[px][o] + bv, 0.f));
      *(ushort8*)(&h2[((size_t)(b * 32 + oc) * 360 + hh) * 640 + tw0 + gx * 8]) = pk;
    }
  }
}

// ---------------- conv3: 3x3, 32->48, SAME, no relu, fused pixel_shuffle(4) ----------------
__global__ __launch_bounds__(384) void conv3_kernel(
    const ushort* __restrict__ h2, const float* __restrict__ w3,
    const float* __restrict__ b3, float* __restrict__ out) {
  __shared__ float xt[8][18][35];
  __shared__ float wt[48][8][9];
  const int tw0 = blockIdx.x * 32, th0 = blockIdx.y * 16;
  const int b = blockIdx.z;
  const int t = threadIdx.x;
  const int slot = t & 63, ocg = t >> 6;   // 0..5 -> 48 oc
  const int gx = slot & 3, gy = slot >> 2;
  float acc[8][8];
#pragma unroll
  for (int px = 0; px < 8; ++px)
#pragma unroll
    for (int o = 0; o < 8; ++o) acc[px][o] = 0.f;
  for (int cc = 0; cc < 4; ++cc) {
    __syncthreads();
    for (int e = t; e < 8 * 18 * 34; e += 384) {
      int ci = e / 612, rm = e - ci * 612, r = rm / 34, cL = rm - r * 34;
      int hh = th0 + r - 1, ww = tw0 + cL - 1;
      float v = 0.f;
      if (hh >= 0 && hh < 360 && ww >= 0 && ww < 640)
        v = bf2f(h2[((b * 32 + cc * 8 + ci) * 360 + hh) * 640 + ww]);
      xt[ci][r][cL] = v;
    }
    for (int e = t; e < 48 * 8 * 9; e += 384) {
      int o = e / 72, rm = e - o * 72, ci = rm / 9, k = rm - ci * 9;
      wt[o][ci][k] = w3[(o * 32 + cc * 8 + ci) * 9 + k];
    }
    __syncthreads();
#pragma unroll 1
    for (int ci = 0; ci < 8; ++ci) {
#pragma unroll
      for (int ki = 0; ki < 3; ++ki) {
        float xv[10];
#pragma unroll
        for (int u = 0; u < 10; ++u) xv[u] = xt[ci][gy + ki][gx * 8 + u];
#pragma unroll
        for (int kj = 0; kj < 3; ++kj) {
          float wr[8];
#pragma unroll
          for (int o = 0; o < 8; ++o) wr[o] = wt[ocg * 8 + o][ci][ki * 3 + kj];
#pragma unroll
          for (int px = 0; px < 8; ++px)
#pragma unroll
            for (int o = 0; o < 8; ++o)
              acc[px][o] = fmaf(xv[px + kj], wr[o], acc[px][o]);
        }
      }
    }
  }
  const int hh = th0 + gy;
  if (hh < 360) {
#pragma unroll
    for (int o = 0; o < 8; ++o) {
      int oc = ocg * 8 + o;
      float bv = b3[oc];
      int c = oc >> 4, r1 = (oc >> 2) & 3, r2 = oc & 3;
      float* dst = out + ((size_t)(b * 3 + c) * 1440 + hh * 4 + r1) * 2560 + (size_t)(tw0 + gx * 8) * 4 + r2;
#pragma unroll
      for (int px = 0; px < 8; ++px) dst[px * 4] = acc[px][o] + bv;
    }
  }
}

extern "C" void kernel_launch(void* const* d_in, const int* in_sizes, int n_in,
                              void* d_out, int out_size, void* d_ws, size_t ws_size,
                              hipStream_t stream) {
  const float* x      = (const float*)d_in[0];
  const float* w_feat = (const float*)d_in[1];
  const float* b_feat = (const float*)d_in[2];
  const float* w_kern = (const float*)d_in[3];
  const float* b_kern = (const float*)d_in[4];
  const float* w_badp = (const float*)d_in[5];
  const float* b_badp = (const float*)d_in[6];
  const float* w1 = (const float*)d_in[7];
  const float* b1 = (const float*)d_in[8];
  const float* w2 = (const float*)d_in[9];
  const float* b2 = (const float*)d_in[10];
  const float* w3 = (const float*)d_in[11];
  const float* b3 = (const float*)d_in[12];

  // ws layout (bytes), total 184,618,496:
  //  [0, 117964800)        : feat bf16 (84,934,656) then reused as h1 bf16 (117,964,800)
  //  [117964800, 150994944): kernbias bf16 (33,030,144) then reused as h2 bf16 (29,491,200)
  //  [150994944, 180486144): sp bf16 (29,491,200)
  //  [180486144, 184614912): Bt bf16 (4,128,768)
  //  [184614912, 184618496): bias896 f32
  char* ws = (char*)d_ws;
  ushort* feat     = (ushort*)(ws);
  ushort* h1       = (ushort*)(ws);
  ushort* kernbias = (ushort*)(ws + 117964800);
  ushort* h2       = (ushort*)(ws + 117964800);
  ushort* sp       = (ushort*)(ws + 150994944);
  ushort* Bt       = (ushort*)(ws + 180486144);
  float*  bias896  = (float*)(ws + 184614912);

  pack_kernel<<<(896 * 2304 + 896 + 255) / 256, 256, 0, stream>>>(
      w_kern, b_kern, w_badp, b_badp, Bt, bias896);
  feat_kernel<<<4608, 256, 0, stream>>>(x, w_feat, b_feat, feat);
  gemm_kernel<<<dim3(144, 7), 256, 0, stream>>>(feat, Bt, bias896, kernbias);
  apply_kernel<<<2304, 256, 0, stream>>>(x, kernbias, sp);
  conv1_kernel<<<dim3(20, 23, 8), 256, 0, stream>>>(sp, w1, b1, h1);
  conv2_kernel<<<dim3(20, 23, 2), 256, 0, stream>>>(h1, w2, b2, h2);
  conv3_kernel<<<dim3(20, 23, 2), 384, 0, stream>>>(h2, w3, b3, (float*)d_out);
}

// Round 2
// 565.283 us; speedup vs baseline: 4.1932x; 4.1932x over previous
//
#include <hip/hip_runtime.h>
#include <stdint.h>

typedef unsigned short ushort;
typedef __bf16 bf16x8 __attribute__((ext_vector_type(8)));
typedef float f32x4 __attribute__((ext_vector_type(4)));
typedef ushort ushort8 __attribute__((ext_vector_type(8)));

__device__ __forceinline__ float bf2f(ushort u) {
  union { unsigned int i; float f; } v; v.i = ((unsigned int)u) << 16; return v.f;
}
__device__ __forceinline__ ushort f2bf(float f) {
  union { float f; unsigned int i; } v; v.f = f;
  unsigned int r = v.i + 0x7fffu + ((v.i >> 16) & 1u);
  return (ushort)(r >> 16);
}

// ---------------- pack: Bt[896][2304] bf16 + bias896 ----------------
__global__ __launch_bounds__(256) void pack_kernel(
    const float* __restrict__ w_kern, const float* __restrict__ b_kern,
    const float* __restrict__ w_badp, const float* __restrict__ b_badp,
    ushort* __restrict__ Bt, float* __restrict__ bias896) {
  int idx = blockIdx.x * 256 + threadIdx.x;
  const int total = 896 * 2304;
  if (idx < total) {
    int o = idx / 2304, k = idx - o * 2304;
    int c = k & 255, pos = k >> 8;
    float v = (o < 864) ? w_kern[(o * 256 + c) * 9 + pos]
                        : w_badp[((o - 864) * 256 + c) * 9 + pos];
    Bt[idx] = f2bf(v);
  } else if (idx < total + 896) {
    int o = idx - total;
    bias896[o] = (o < 864) ? b_kern[o] : b_badp[o - 864];
  }
}

// ---------------- pack2: conv weights -> [tap][oc][ic] bf16 ----------------
__global__ __launch_bounds__(256) void pack2_kernel(
    const float* __restrict__ w1, const float* __restrict__ w2,
    const float* __restrict__ w3, ushort* __restrict__ wp1,
    ushort* __restrict__ wp2, ushort* __restrict__ wp3) {
  int idx = blockIdx.x * 256 + threadIdx.x;
  if (idx < 102400) {                       // wp1 [25][128][32] <- w1[o][c][tap]
    int t = idx >> 12, rm = idx & 4095, o = rm >> 5, c = rm & 31;
    wp1[idx] = f2bf(w1[(o * 32 + c) * 25 + t]);
  } else if (idx < 102400 + 36864) {        // wp2 [9][32][128]
    int j = idx - 102400;
    int t = j >> 12, rm = j & 4095, o = rm >> 7, c = rm & 127;
    wp2[j] = f2bf(w2[(o * 128 + c) * 9 + t]);
  } else if (idx < 102400 + 36864 + 13824) {// wp3 [9][48][32]
    int j = idx - 139264;
    int t = j / 1536, rm = j - t * 1536, o = rm >> 5, c = rm & 31;
    wp3[j] = f2bf(w3[(o * 32 + c) * 9 + t]);
  }
}

// ---------------- feat: per-patch 3x3 VALID conv, 256 ch, relu, bf16 ----------------
__global__ __launch_bounds__(256) void feat_kernel(
    const float* __restrict__ x, const float* __restrict__ w_feat,
    const float* __restrict__ b_feat, ushort* __restrict__ feat) {
  __shared__ float xp[4][3][5][5];
  const int t = threadIdx.x;
  const int n0 = blockIdx.x * 4;
  for (int e = t; e < 300; e += 256) {
    int p = e / 75, rem = e - p * 75;
    int ci = rem / 25, r = rem - ci * 25, i = r / 5, j = r - i * 5;
    int n = n0 + p;
    int b = n / 9216, ph = (n >> 7) % 72, pw = n & 127;
    xp[p][ci][i][j] = x[((b * 3 + ci) * 360 + ph * 5 + i) * 640 + pw * 5 + j];
  }
  float wf[27];
#pragma unroll
  for (int m = 0; m < 27; ++m) wf[m] = w_feat[t * 27 + m];
  const float bv = b_feat[t];
  __syncthreads();
  for (int p = 0; p < 4; ++p) {
    ushort* dst = feat + (size_t)(n0 + p) * 2304 + t;
#pragma unroll
    for (int pi = 0; pi < 3; ++pi)
#pragma unroll
      for (int pj = 0; pj < 3; ++pj) {
        float acc = bv;
#pragma unroll
        for (int ci = 0; ci < 3; ++ci)
#pragma unroll
          for (int ki = 0; ki < 3; ++ki)
#pragma unroll
            for (int kj = 0; kj < 3; ++kj)
              acc = fmaf(xp[p][ci][pi + ki][pj + kj], wf[ci * 9 + ki * 3 + kj], acc);
        dst[(pi * 3 + pj) * 256] = f2bf(fmaxf(acc, 0.f));
      }
  }
}

// ---------------- kern+badp GEMM: MFMA bf16, 128x128 tile, BK=32 ----------------
__global__ __launch_bounds__(256) void gemm_kernel(
    const ushort* __restrict__ A, const ushort* __restrict__ Bt,
    const float* __restrict__ bias, ushort* __restrict__ C) {
  const int K = 2304, N = 896;
  __shared__ __align__(16) ushort lA[128 * 32];
  __shared__ __align__(16) ushort lB[128 * 32];
  const int m0 = blockIdx.x * 128, n0 = blockIdx.y * 128;
  const int t = threadIdx.x;
  const int lane = t & 63, wave = t >> 6;
  const int wm = wave >> 1, wn = wave & 1;
  f32x4 acc[4][4] = {};
  const ushort* gA = A + (m0 + (t >> 2)) * K + (t & 3) * 8;
  const ushort* gB = Bt + (n0 + (t >> 2)) * K + (t & 3) * 8;
  ushort* sA = &lA[t * 8];
  ushort* sB = &lB[t * 8];
  const int aoff = (wm * 64 + (lane & 15)) * 32 + (lane >> 4) * 8;
  const int boff = (wn * 64 + (lane & 15)) * 32 + (lane >> 4) * 8;
  for (int kt = 0; kt < K; kt += 32) {
    ushort8 a0 = *(const ushort8*)(gA + kt);
    ushort8 a1 = *(const ushort8*)(gA + 64 * K + kt);
    ushort8 b0 = *(const ushort8*)(gB + kt);
    ushort8 b1 = *(const ushort8*)(gB + 64 * K + kt);
    __syncthreads();
    *(ushort8*)sA = a0;
    *(ushort8*)(sA + 2048) = a1;
    *(ushort8*)sB = b0;
    *(ushort8*)(sB + 2048) = b1;
    __syncthreads();
    bf16x8 af[4], bfr[4];
#pragma unroll
    for (int mi = 0; mi < 4; ++mi) {
      ushort8 tmp = *(const ushort8*)(&lA[aoff + mi * 512]);
      af[mi] = __builtin_bit_cast(bf16x8, tmp);
    }
#pragma unroll
    for (int ni = 0; ni < 4; ++ni) {
      ushort8 tmp = *(const ushort8*)(&lB[boff + ni * 512]);
      bfr[ni] = __builtin_bit_cast(bf16x8, tmp);
    }
#pragma unroll
    for (int mi = 0; mi < 4; ++mi)
#pragma unroll
      for (int ni = 0; ni < 4; ++ni)
        acc[mi][ni] = __builtin_amdgcn_mfma_f32_16x16x32_bf16(af[mi], bfr[ni], acc[mi][ni], 0, 0, 0);
  }
#pragma unroll
  for (int ni = 0; ni < 4; ++ni) {
    int col = n0 + wn * 64 + ni * 16 + (lane & 15);
    float bv = bias[col];
#pragma unroll
    for (int mi = 0; mi < 4; ++mi) {
      int row0 = m0 + wm * 64 + mi * 16 + (lane >> 4) * 4;
#pragma unroll
      for (int r = 0; r < 4; ++r)
        C[(size_t)(row0 + r) * N + col] = f2bf(acc[mi][ni][r] + bv);
    }
  }
}

// ---------------- apply: einsum + bias, relu, batch_to_space -> sp NHWC ----------------
__global__ __launch_bounds__(256) void apply_kernel(
    const float* __restrict__ x, const ushort* __restrict__ kernbias,
    ushort* __restrict__ sp) {
  __shared__ float xp[8][3][7][7];
  __shared__ ushort outl[8][32][25];
  const int t = threadIdx.x;
  const int n0 = blockIdx.x * 8;
  const int b = n0 / 9216, ph = (n0 >> 7) % 72, pw0 = n0 & 127;
  for (int e = t; e < 8 * 3 * 49; e += 256) ((float*)xp)[e] = 0.f;
  __syncthreads();
  for (int e = t; e < 600; e += 256) {
    int p = e / 75, rem = e - p * 75;
    int ci = rem / 25, r = rem - ci * 25, i = r / 5, j = r - i * 5;
    xp[p][ci][i + 1][j + 1] = x[((b * 3 + ci) * 360 + ph * 5 + i) * 640 + (pw0 + p) * 5 + j];
  }
  __syncthreads();
  const int p = t >> 5, f = t & 31;
  const int n = n0 + p;
  float kk[27];
#pragma unroll
  for (int k = 0; k < 27; ++k) kk[k] = bf2f(kernbias[(size_t)n * 896 + f * 27 + k]);
  const float bv = bf2f(kernbias[(size_t)n * 896 + 864 + f]);
  for (int l = 0; l < 25; ++l) {
    int li = l / 5, lj = l - li * 5;
    float s = bv;
#pragma unroll
    for (int k = 0; k < 27; ++k) {
      int ci = k / 9, rm = k - ci * 9, ki = rm / 3, kj = rm - ki * 3;
      s = fmaf(xp[p][ci][li + ki][lj + kj], kk[k], s);
    }
    outl[p][f][l] = f2bf(fmaxf(s, 0.f));
  }
  __syncthreads();
  // NHWC write: sp[b][h][w][c], c fastest -> coalesced
  for (int e = t; e < 6400; e += 256) {
    int f2 = e & 31;
    int idx = e >> 5;                 // 0..199
    int i = idx / 40, c40 = idx - i * 40;
    int pp = c40 / 5, j = c40 - pp * 5;
    sp[(((size_t)b * 360 + ph * 5 + i) * 640 + pw0 * 5 + c40) * 32 + f2] = outl[pp][f2][i * 5 + j];
  }
}

// ---------------- conv1: 5x5, 32->128, MFMA implicit GEMM, NHWC ----------------
// tile: 2h x 64w x 128oc; 4 waves: (wh, wn)
__global__ __launch_bounds__(256) void conv1_kernel(
    const ushort* __restrict__ sp, const ushort* __restrict__ wp1,
    const float* __restrict__ b1, ushort* __restrict__ h1) {
  __shared__ ushort8 lin[6 * 4 * 69];   // [r<6][c8<4][wx pad 69], 16B units
  const int t = threadIdx.x;
  const int lane = t & 63, wave = t >> 6;
  const int wh = wave >> 1, wn = wave & 1;
  const int w0 = blockIdx.x * 64, h0 = blockIdx.y * 2, b = blockIdx.z;
  // stage input rows h0-2 .. h0+3, cols w0-2 .. w0+65
  for (int u = t; u < 6 * 4 * 68; u += 256) {
    int c8 = u & 3, rest = u >> 2;
    int wx = rest % 68, r = rest / 68;
    int gh = h0 - 2 + r, gw = w0 - 2 + wx;
    ushort8 v = {};
    if (gh >= 0 && gh < 360 && gw >= 0 && gw < 640)
      v = *(const ushort8*)(sp + (((size_t)b * 360 + gh) * 640 + gw) * 32 + c8 * 8);
    lin[(r * 4 + c8) * 69 + wx] = v;
  }
  __syncthreads();
  f32x4 acc[4][4] = {};
  const int abase = (lane >> 4) * 69 + (lane & 15);
  const ushort* wbase = wp1 + (wn * 64 + (lane & 15)) * 32 + (lane >> 4) * 8;
#pragma unroll 1
  for (int ki = 0; ki < 5; ++ki) {
#pragma unroll
    for (int kj = 0; kj < 5; ++kj) {
      const int tap = ki * 5 + kj;
      bf16x8 bfr[4];
#pragma unroll
      for (int nf = 0; nf < 4; ++nf) {
        ushort8 tmp = *(const ushort8*)(wbase + (size_t)tap * 4096 + nf * 512);
        bfr[nf] = __builtin_bit_cast(bf16x8, tmp);
      }
      bf16x8 afr[4];
#pragma unroll
      for (int mf = 0; mf < 4; ++mf)
        afr[mf] = __builtin_bit_cast(bf16x8, lin[(wh + ki) * 276 + abase + mf * 16 + kj]);
#pragma unroll
      for (int mf = 0; mf < 4; ++mf)
#pragma unroll
        for (int nf = 0; nf < 4; ++nf)
          acc[mf][nf] = __builtin_amdgcn_mfma_f32_16x16x32_bf16(afr[mf], bfr[nf], acc[mf][nf], 0, 0, 0);
    }
  }
  const int h = h0 + wh;
#pragma unroll
  for (int nf = 0; nf < 4; ++nf) {
    int oc = wn * 64 + nf * 16 + (lane & 15);
    float bv = b1[oc];
#pragma unroll
    for (int mf = 0; mf < 4; ++mf) {
      int w = w0 + mf * 16 + ((lane >> 4) << 2);
      size_t base = (((size_t)b * 360 + h) * 640 + w) * 128 + oc;
#pragma unroll
      for (int r = 0; r < 4; ++r)
        h1[base + (size_t)r * 128] = f2bf(fmaxf(acc[mf][nf][r] + bv, 0.f));
    }
  }
}

// ---------------- conv2: 3x3, 128->32, MFMA implicit GEMM, NHWC ----------------
// tile: 4h x 32w x 32oc; 4 waves = 4 h rows
__global__ __launch_bounds__(256) void conv2_kernel(
    const ushort* __restrict__ h1, const ushort* __restrict__ wp2,
    const float* __restrict__ b2, ushort* __restrict__ h2) {
  __shared__ ushort8 lin[6 * 16 * 35];  // [r<6][c8<16][wx pad 35]
  const int t = threadIdx.x;
  const int lane = t & 63, wh = t >> 6;
  const int w0 = blockIdx.x * 32, h0 = blockIdx.y * 4, b = blockIdx.z;
  for (int u = t; u < 6 * 16 * 34; u += 256) {
    int c8 = u & 15, rest = u >> 4;
    int wx = rest % 34, r = rest / 34;
    int gh = h0 - 1 + r, gw = w0 - 1 + wx;
    ushort8 v = {};
    if (gh >= 0 && gh < 360 && gw >= 0 && gw < 640)
      v = *(const ushort8*)(h1 + (((size_t)b * 360 + gh) * 640 + gw) * 128 + c8 * 8);
    lin[(r * 16 + c8) * 35 + wx] = v;
  }
  __syncthreads();
  f32x4 acc[2][2] = {};
  const ushort* wbase = wp2 + ((lane & 15)) * 128 + (lane >> 4) * 8;
#pragma unroll 1
  for (int ki = 0; ki < 3; ++ki) {
#pragma unroll
    for (int kj = 0; kj < 3; ++kj) {
      const int tap = ki * 3 + kj;
#pragma unroll
      for (int cb = 0; cb < 4; ++cb) {
        bf16x8 bfr[2];
#pragma unroll
        for (int nf = 0; nf < 2; ++nf) {
          ushort8 tmp = *(const ushort8*)(wbase + (size_t)tap * 4096 + nf * 2048 + cb * 32);
          bfr[nf] = __builtin_bit_cast(bf16x8, tmp);
        }
        bf16x8 afr[2];
#pragma unroll
        for (int mf = 0; mf < 2; ++mf)
          afr[mf] = __builtin_bit_cast(bf16x8,
              lin[(wh + ki) * 560 + (cb * 4 + (lane >> 4)) * 35 + mf * 16 + (lane & 15) + kj]);
#pragma unroll
        for (int mf = 0; mf < 2; ++mf)
#pragma unroll
          for (int nf = 0; nf < 2; ++nf)
            acc[mf][nf] = __builtin_amdgcn_mfma_f32_16x16x32_bf16(afr[mf], bfr[nf], acc[mf][nf], 0, 0, 0);
      }
    }
  }
  const int h = h0 + wh;
#pragma unroll
  for (int nf = 0; nf < 2; ++nf) {
    int oc = nf * 16 + (lane & 15);
    float bv = b2[oc];
#pragma unroll
    for (int mf = 0; mf < 2; ++mf) {
      int w = w0 + mf * 16 + ((lane >> 4) << 2);
      size_t base = (((size_t)b * 360 + h) * 640 + w) * 32 + oc;
#pragma unroll
      for (int r = 0; r < 4; ++r)
        h2[base + (size_t)r * 32] = f2bf(fmaxf(acc[mf][nf][r] + bv, 0.f));
    }
  }
}

// ---------------- conv3: 3x3, 32->48, MFMA, fp32 out + fused pixel_shuffle ----------------
// tile: 2h x 64w x 48oc; 4 waves: (wh, wm)
__global__ __launch_bounds__(256) void conv3_kernel(
    const ushort* __restrict__ h2, const ushort* __restrict__ wp3,
    const float* __restrict__ b3, float* __restrict__ out) {
  __shared__ ushort8 lin[4 * 4 * 67];   // [r<4][c8<4][wx pad 67]
  const int t = threadIdx.x;
  const int lane = t & 63, wave = t >> 6;
  const int wh = wave & 1, wm = wave >> 1;
  const int w0 = blockIdx.x * 64, h0 = blockIdx.y * 2, b = blockIdx.z;
  for (int u = t; u < 4 * 4 * 66; u += 256) {
    int c8 = u & 3, rest = u >> 2;
    int wx = rest % 66, r = rest / 66;
    int gh = h0 - 1 + r, gw = w0 - 1 + wx;
    ushort8 v = {};
    if (gh >= 0 && gh < 360 && gw >= 0 && gw < 640)
      v = *(const ushort8*)(h2 + (((size_t)b * 360 + gh) * 640 + gw) * 32 + c8 * 8);
    lin[(r * 4 + c8) * 67 + wx] = v;
  }
  __syncthreads();
  f32x4 acc[2][3] = {};
  const int abase = (lane >> 4) * 67 + wm * 32 + (lane & 15);
  const ushort* wbase = wp3 + ((lane & 15)) * 32 + (lane >> 4) * 8;
#pragma unroll 1
  for (int ki = 0; ki < 3; ++ki) {
#pragma unroll
    for (int kj = 0; kj < 3; ++kj) {
      const int tap = ki * 3 + kj;
      bf16x8 bfr[3];
#pragma unroll
      for (int nf = 0; nf < 3; ++nf) {
        ushort8 tmp = *(const ushort8*)(wbase + (size_t)tap * 1536 + nf * 512);
        bfr[nf] = __builtin_bit_cast(bf16x8, tmp);
      }
      bf16x8 afr[2];
#pragma unroll
      for (int mf = 0; mf < 2; ++mf)
        afr[mf] = __builtin_bit_cast(bf16x8, lin[(wh + ki) * 268 + abase + mf * 16 + kj]);
#pragma unroll
      for (int mf = 0; mf < 2; ++mf)
#pragma unroll
        for (int nf = 0; nf < 3; ++nf)
          acc[mf][nf] = __builtin_amdgcn_mfma_f32_16x16x32_bf16(afr[mf], bfr[nf], acc[mf][nf], 0, 0, 0);
    }
  }
  const int h = h0 + wh;
#pragma unroll
  for (int nf = 0; nf < 3; ++nf) {
    int oc = nf * 16 + (lane & 15);
    float bv = b3[oc];
    int c = oc >> 4, r1 = (oc >> 2) & 3, r2 = oc & 3;
#pragma unroll
    for (int mf = 0; mf < 2; ++mf) {
      int wb = w0 + wm * 32 + mf * 16 + ((lane >> 4) << 2);
#pragma unroll
      for (int r = 0; r < 4; ++r) {
        int w = wb + r;
        out[(((size_t)b * 3 + c) * 1440 + h * 4 + r1) * 2560 + (size_t)w * 4 + r2] =
            acc[mf][nf][r] + bv;
      }
    }
  }
}

extern "C" void kernel_launch(void* const* d_in, const int* in_sizes, int n_in,
                              void* d_out, int out_size, void* d_ws, size_t ws_size,
                              hipStream_t stream) {
  const float* x      = (const float*)d_in[0];
  const float* w_feat = (const float*)d_in[1];
  const float* b_feat = (const float*)d_in[2];
  const float* w_kern = (const float*)d_in[3];
  const float* b_kern = (const float*)d_in[4];
  const float* w_badp = (const float*)d_in[5];
  const float* b_badp = (const float*)d_in[6];
  const float* w1 = (const float*)d_in[7];
  const float* b1 = (const float*)d_in[8];
  const float* w2 = (const float*)d_in[9];
  const float* b2 = (const float*)d_in[10];
  const float* w3 = (const float*)d_in[11];
  const float* b3 = (const float*)d_in[12];

  // ws layout (bytes), total 184,618,496 (same bound as round 1):
  //  A [0, 117964800)          : feat bf16 (84.9MB) -> h1 NHWC bf16 (118MB)
  //  B [117964800, 150994944)  : kernbias bf16 (33MB) -> h2 NHWC bf16 (29.5MB) + wp1/2/3 at tail
  //  C [150994944, 180486144)  : sp NHWC bf16 (29.5MB)
  //  D [180486144, 184618496)  : Bt bf16 (4.13MB) + bias896 f32
  char* ws = (char*)d_ws;
  ushort* feat     = (ushort*)(ws);
  ushort* h1       = (ushort*)(ws);
  ushort* kernbias = (ushort*)(ws + 117964800);
  ushort* h2       = (ushort*)(ws + 117964800);
  ushort* wp1      = (ushort*)(ws + 147456000);
  ushort* wp2      = (ushort*)(ws + 147660800);
  ushort* wp3      = (ushort*)(ws + 147734528);
  ushort* sp       = (ushort*)(ws + 150994944);
  ushort* Bt       = (ushort*)(ws + 180486144);
  float*  bias896  = (float*)(ws + 184614912);

  pack_kernel<<<(896 * 2304 + 896 + 255) / 256, 256, 0, stream>>>(
      w_kern, b_kern, w_badp, b_badp, Bt, bias896);
  feat_kernel<<<4608, 256, 0, stream>>>(x, w_feat, b_feat, feat);
  gemm_kernel<<<dim3(144, 7), 256, 0, stream>>>(feat, Bt, bias896, kernbias);
  apply_kernel<<<2304, 256, 0, stream>>>(x, kernbias, sp);
  pack2_kernel<<<598, 256, 0, stream>>>(w1, w2, w3, wp1, wp2, wp3);
  conv1_kernel<<<dim3(10, 180, 2), 256, 0, stream>>>(sp, wp1, b1, h1);
  conv2_kernel<<<dim3(20, 90, 2), 256, 0, stream>>>(h1, wp2, b2, h2);
  conv3_kernel<<<dim3(10, 180, 2), 256, 0, stream>>>(h2, wp3, b3, (float*)d_out);
}